// Round 3
// baseline (80.078 us; speedup 1.0000x reference)
//
#include <hip/hip_runtime.h>
#include <cmath>

namespace {

typedef float f2 __attribute__((ext_vector_type(2)));

constexpr int BATCH  = 32;
constexpr int NPOSE  = 2048;
constexpr int KSAMP  = 32;             // samples per segment
constexpr int NSEG   = NPOSE - 1;      // 2047 segments
constexpr int NDELTA = NPOSE + 1;      // 2049 deltas
constexpr int SEGW   = 8;              // segments per WAVE (wave-autonomous unit)
constexpr int WAVES  = 4;              // waves per block
constexpr int SEGB   = SEGW * WAVES;   // 32 segments per block
constexpr int RSTRIDE = 6;             // float4s per delta record (24 words)
constexpr float EPS  = 1e-6f;
constexpr float EPS2 = 1e-12f;
constexpr float INV_TWO_PI = 0.15915494309189535f;

struct V3 { float x, y, z; };
struct Q4 { float x, y, z, w; };

__device__ __forceinline__ float frcp(float x)  { return __builtin_amdgcn_rcpf(x); }
__device__ __forceinline__ float fsqrt(float x) { return __builtin_amdgcn_sqrtf(x); }
__device__ __forceinline__ float fsin(float x)  { return __builtin_amdgcn_sinf(x * INV_TWO_PI); }
__device__ __forceinline__ float fcos(float x)  { return __builtin_amdgcn_cosf(x * INV_TWO_PI); }

__device__ __forceinline__ V3 v3add(V3 a, V3 b) { return {a.x + b.x, a.y + b.y, a.z + b.z}; }
__device__ __forceinline__ V3 v3sub(V3 a, V3 b) { return {a.x - b.x, a.y - b.y, a.z - b.z}; }
__device__ __forceinline__ V3 v3scl(V3 a, float s) { return {a.x * s, a.y * s, a.z * s}; }
__device__ __forceinline__ float v3dot(V3 a, V3 b) { return a.x * b.x + a.y * b.y + a.z * b.z; }
__device__ __forceinline__ V3 v3cross(V3 a, V3 b) {
    return {a.y * b.z - a.z * b.y, a.z * b.x - a.x * b.z, a.x * b.y - a.y * b.x};
}

__device__ __forceinline__ V3 qrot(Q4 q, V3 v) {
    V3 qv{q.x, q.y, q.z};
    V3 t = v3scl(v3cross(qv, v), 2.0f);
    return v3add(v3add(v, v3scl(t, q.w)), v3cross(qv, t));
}

__device__ __forceinline__ Q4 qmul(Q4 a, Q4 b) {
    return {a.w * b.x + a.x * b.w + a.y * b.z - a.z * b.y,
            a.w * b.y + a.y * b.w + a.z * b.x - a.x * b.z,
            a.w * b.z + a.z * b.w + a.x * b.y - a.y * b.x,
            a.w * b.w - a.x * b.x - a.y * b.y - a.z * b.z};
}

// fast acos, |err| <~ 7e-5 rad; for unit quats atan2(|qv|, w) == acos(w)
__device__ __forceinline__ float facos(float x) {
    float ax = fabsf(x);
    float p = -0.0012624911f;
    p = p * ax + 0.0066700901f;
    p = p * ax - 0.0170881256f;
    p = p * ax + 0.0308918810f;
    p = p * ax - 0.0501743046f;
    p = p * ax + 0.0889789874f;
    p = p * ax - 0.2145988016f;
    p = p * ax + 1.5707963050f;
    float r = fsqrt(fmaxf(1.0f - ax, 0.0f)) * p;
    return (x >= 0.0f) ? r : (3.14159265358979f - r);
}

__device__ __forceinline__ V3 so3_log(Q4 q) {
    V3 qv{q.x, q.y, q.z};
    float n2 = v3dot(qv, qv);
    bool small = n2 < EPS2;
    float n = fsqrt(small ? 1.0f : n2);
    float iw = frcp(q.w);
    float f_small = 2.0f * iw - (2.0f / 3.0f) * n2 * iw * iw * iw;
    float wc = fminf(fmaxf(q.w, -1.0f), 1.0f);
    float f_big = 2.0f * facos(wc) * frcp(n);
    return v3scl(qv, small ? f_small : f_big);
}

__device__ __forceinline__ V3 jl_inv(V3 phi, V3 v) {
    float t2 = v3dot(phi, phi);
    bool small = t2 < EPS2;
    float t2s = small ? 1.0f : t2;
    float theta = fsqrt(t2s);
    float s = fsin(theta), cth = fcos(theta);
    float s_safe = (fabsf(s) < EPS) ? EPS : s;
    float c_big = frcp(t2s) - (1.0f + cth) * frcp(2.0f * theta * s_safe);
    float c = small ? (1.0f / 12.0f + t2 * (1.0f / 720.0f)) : c_big;
    V3 c1 = v3cross(phi, v);
    return v3add(v3sub(v, v3scl(c1, 0.5f)), v3scl(v3cross(phi, c1), c));
}

// ---- packed-fp32 SE(3) over 2 k-samples (lanes of each f2) ----
struct V3p { f2 x, y, z; };
struct Q4p { f2 x, y, z, w; };
struct SE3p { V3p t; Q4p q; };

__device__ __forceinline__ f2 splat(float a) { return f2{a, a}; }

__device__ __forceinline__ SE3p se3_mul_p(const SE3p& A, const SE3p& B) {
    f2 cx = A.q.y * B.t.z - A.q.z * B.t.y;
    f2 cy = A.q.z * B.t.x - A.q.x * B.t.z;
    f2 cz = A.q.x * B.t.y - A.q.y * B.t.x;
    cx = cx + cx; cy = cy + cy; cz = cz + cz;
    SE3p r;
    r.t.x = A.t.x + B.t.x + A.q.w * cx + (A.q.y * cz - A.q.z * cy);
    r.t.y = A.t.y + B.t.y + A.q.w * cy + (A.q.z * cx - A.q.x * cz);
    r.t.z = A.t.z + B.t.z + A.q.w * cz + (A.q.x * cy - A.q.y * cx);
    r.q.x = A.q.w * B.q.x + A.q.x * B.q.w + A.q.y * B.q.z - A.q.z * B.q.y;
    r.q.y = A.q.w * B.q.y + A.q.y * B.q.w + A.q.z * B.q.x - A.q.x * B.q.z;
    r.q.z = A.q.w * B.q.z + A.q.z * B.q.w + A.q.x * B.q.y - A.q.y * B.q.x;
    r.q.w = A.q.w * B.q.w - A.q.x * B.q.x - A.q.y * B.q.y - A.q.z * B.q.z;
    return r;
}

__device__ __forceinline__ SE3p build_E(const float4& A, const float4& U,
                                        const float4& C1, const float4& C2,
                                        float wa, float wb) {
    const float inv_n = U.w;                   // per-delta 1/nphi
    float tha = wa * A.w, thb = wb * A.w;      // th = w * nphi
    float sa = fsin(0.5f * tha), ca = fcos(0.5f * tha);
    float sb = fsin(0.5f * thb), cb = fcos(0.5f * thb);
    float cAa = 2.0f * sa * sa * inv_n;        // (1 - cos th)/n
    float cAb = 2.0f * sb * sb * inv_n;
    float cBa = (tha - 2.0f * sa * ca) * inv_n; // (th - sin th)/n
    float cBb = (thb - 2.0f * sb * cb) * inv_n;
    f2 s2{sa, sb}, c2{ca, cb};
    f2 cA{cAa, cAb}, cB{cBa, cBb}, wh{wa, wb};
    SE3p E;
    E.q.x = s2 * splat(U.x); E.q.y = s2 * splat(U.y); E.q.z = s2 * splat(U.z);
    E.q.w = c2;
    E.t.x = wh * splat(A.x) + cA * splat(C1.x) + cB * splat(C2.x);
    E.t.y = wh * splat(A.y) + cA * splat(C1.y) + cB * splat(C2.y);
    E.t.z = wh * splat(A.z) + cA * splat(C1.z) + cB * splat(C2.z);
    return E;
}

// ---------------- wave-autonomous fused kernel (ZERO barriers) ----------------
// Each 64-lane wave owns 8 segments end-to-end:
//   A: lanes 0..9 compute the 10 delta records its segments need -> private LDS slice
//   B: lane = (segl 0..7, k-quad 0..7) packed-fp32 compose -> private LDS stage slice
//   C: wave copies its own 7KB stage slice to global, stride-1 float4
// All LDS dependencies are same-wave (DS ops execute in order; compiler inserts
// lgkmcnt), so no __syncthreads. Waves across the CU free-run at different
// phases -> VALU (B) and HBM stores (C) pipeline instead of bulk-sync aligning.
__global__ __launch_bounds__(256) void lie_spline_fused(
    const float* __restrict__ poses,   // [B, N, 7]
    const float* __restrict__ timev,   // [K]
    float* __restrict__ out)           // [B, S*K, 7]
{
    __shared__ float4 sdel[WAVES][(SEGW + 2) * RSTRIDE];          // 3840 B
    __shared__ __align__(16) float stage[WAVES][SEGW * KSAMP * 7];// 28672 B (32.5KB -> 5 blk/CU by LDS)

    const int b    = blockIdx.y;
    const int tid  = threadIdx.x;
    const int wid  = tid >> 6;                   // wave 0..3
    const int lane = tid & 63;
    const int sW   = blockIdx.x * SEGB + wid * SEGW;   // wave's first segment
    const int segl = lane >> 3;                  // 0..7 within wave
    const int m    = lane & 7;                   // k-quad index

    const float4 uvec = reinterpret_cast<const float4*>(timev)[m];

    // ---- Phase A (lanes 0..9 of every wave; exec-masked, ~10/64 active) ----
    if (lane < SEGW + 2) {
        int i = min(sW + lane, NDELTA - 1);
        int ia = max(i - 1, 0);
        int ib = min(i, NPOSE - 1);
        const float* Pa = poses + ((size_t)b * NPOSE + ia) * 7;
        const float* Pb = poses + ((size_t)b * NPOSE + ib) * 7;
        V3 ta{Pa[0], Pa[1], Pa[2]}; Q4 qa{Pa[3], Pa[4], Pa[5], Pa[6]};
        V3 tb{Pb[0], Pb[1], Pb[2]}; Q4 qb{Pb[3], Pb[4], Pb[5], Pb[6]};

        Q4 qi{-qa.x, -qa.y, -qa.z, qa.w};
        V3 trel = qrot(qi, v3sub(tb, ta));
        Q4 qrel = qmul(qi, qb);
        V3 phi = so3_log(qrel);
        V3 tau = jl_inv(phi, trel);

        float nphi = fsqrt(v3dot(phi, phi));
        float inv_n = frcp(fmaxf(nphi, 1e-20f)); // identity: phi=0 -> u=c1=c2=0 exactly
        V3 u  = v3scl(phi, inv_n);
        V3 c1 = v3cross(u, tau);
        V3 c2 = v3cross(u, c1);

        float4* r = sdel[wid] + lane * RSTRIDE;
        r[0] = make_float4(tau.x, tau.y, tau.z, nphi);
        r[1] = make_float4(u.x,  u.y,  u.z,  inv_n);
        r[2] = make_float4(c1.x, c1.y, c1.z, 0.0f);
        r[3] = make_float4(c2.x, c2.y, c2.z, 0.0f);
        r[4] = make_float4(ta.x, ta.y, ta.z, qa.x);   // Pa == p0 of segment (sW+lane)
        r[5] = make_float4(qa.y, qa.z, qa.w, 0.0f);
    }
    // no barrier: same-wave LDS write->read, hardware DS ordering + lgkmcnt

    // ---- Phase B (unguarded: clamped records make segment NSEG.. well-defined;
    //      its stage slice is simply never copied in Phase C) ----
    {
        const float4* R = sdel[wid] + segl * RSTRIDE;
        const float4 A0 = R[0],             U0 = R[1],               C10 = R[2],               C20 = R[3];
        const float4 P03 = R[4],            P46 = R[5];
        const float4 A1 = R[RSTRIDE],       U1 = R[RSTRIDE + 1],     C11 = R[RSTRIDE + 2],     C21 = R[RSTRIDE + 3];
        const float4 A2 = R[2 * RSTRIDE],   U2 = R[2 * RSTRIDE + 1], C12 = R[2 * RSTRIDE + 2], C22 = R[2 * RSTRIDE + 3];

        SE3p Tph;
        Tph.t.x = splat(P03.x); Tph.t.y = splat(P03.y); Tph.t.z = splat(P03.z);
        Tph.q.x = splat(P03.w); Tph.q.y = splat(P46.x); Tph.q.z = splat(P46.y);
        Tph.q.w = splat(P46.z);

        const float c6 = 1.0f / 6.0f;
        #define CHAIN(ua_, ub_, Tdst_)                                           \
        {                                                                        \
            float ua = (ua_), ub = (ub_);                                        \
            float ua2 = ua * ua, ua3 = ua2 * ua;                                 \
            float ub2 = ub * ub, ub3 = ub2 * ub;                                 \
            float w0a = (5.0f + 3.0f * ua - 3.0f * ua2 + ua3) * c6;              \
            float w0b = (5.0f + 3.0f * ub - 3.0f * ub2 + ub3) * c6;              \
            float w1a = (1.0f + 3.0f * ua + 3.0f * ua2 - 2.0f * ua3) * c6;       \
            float w1b = (1.0f + 3.0f * ub + 3.0f * ub2 - 2.0f * ub3) * c6;       \
            float w2a = ua3 * c6, w2b = ub3 * c6;                                \
            SE3p T = se3_mul_p(Tph, build_E(A0, U0, C10, C20, w0a, w0b));        \
            T = se3_mul_p(T, build_E(A1, U1, C11, C21, w1a, w1b));               \
            T = se3_mul_p(T, build_E(A2, U2, C12, C22, w2a, w2b));               \
            Tdst_ = T;                                                           \
        }

        float* sb_ = stage[wid] + segl * (KSAMP * 7) + m * 28;
        float4* sv = reinterpret_cast<float4*>(sb_);
        float2* s2v = reinterpret_cast<float2*>(sb_);

        // pair 0: k = 4m, 4m+1 (lanes [0],[1]); 3x f4 + f2 tail
        {
            SE3p TA;
            CHAIN(uvec.x, uvec.y, TA)
            sv[0]  = make_float4(TA.t.x[0], TA.t.y[0], TA.t.z[0], TA.q.x[0]);
            sv[1]  = make_float4(TA.q.y[0], TA.q.z[0], TA.q.w[0], TA.t.x[1]);
            sv[2]  = make_float4(TA.t.y[1], TA.t.z[1], TA.q.x[1], TA.q.y[1]);
            s2v[6] = make_float2(TA.q.z[1], TA.q.w[1]);
        }
        // pair 1: k = 4m+2, 4m+3; f2 head + 3x f4
        {
            SE3p TB;
            CHAIN(uvec.z, uvec.w, TB)
            s2v[7] = make_float2(TB.t.x[0], TB.t.y[0]);
            sv[4]  = make_float4(TB.t.z[0], TB.q.x[0], TB.q.y[0], TB.q.z[0]);
            sv[5]  = make_float4(TB.q.w[0], TB.t.x[1], TB.t.y[1], TB.t.z[1]);
            sv[6]  = make_float4(TB.q.x[1], TB.q.y[1], TB.q.z[1], TB.q.w[1]);
        }
        #undef CHAIN
    }
    // no barrier: Phase C reads only this wave's own stage slice

    // ---- Phase C (wave copies its own slice; stride-1 float4) ----
    {
        int nseg_w = min(NSEG - sW, SEGW);               // 8, or 7 for the very last wave
        int nvec = nseg_w * (KSAMP * 7 / 4);             // 56 float4 per segment
        const float4* svv = reinterpret_cast<const float4*>(stage[wid]);
        float4* ov = reinterpret_cast<float4*>(out + ((size_t)b * NSEG + sW) * (size_t)(KSAMP * 7));
        for (int j = lane; j < nvec; j += 64) ov[j] = svv[j];
    }
}

} // namespace

extern "C" void kernel_launch(void* const* d_in, const int* in_sizes, int n_in,
                              void* d_out, int out_size, void* d_ws, size_t ws_size,
                              hipStream_t stream) {
    const float* poses = (const float*)d_in[0];   // [32, 2048, 7] fp32
    const float* timev = (const float*)d_in[1];   // [32] fp32
    float* out = (float*)d_out;                   // [32, 2047*32, 7] fp32
    (void)in_sizes; (void)n_in; (void)out_size; (void)d_ws; (void)ws_size;

    dim3 grid((NSEG + SEGB - 1) / SEGB, BATCH);   // (64, 32)
    lie_spline_fused<<<grid, 256, 0, stream>>>(poses, timev, out);
}

// Round 5
// 77.976 us; speedup vs baseline: 1.0270x; 1.0270x over previous
//
#include <hip/hip_runtime.h>
#include <cmath>

namespace {

typedef float f2 __attribute__((ext_vector_type(2)));
typedef float f4 __attribute__((ext_vector_type(4)));   // native clang vector: OK for nontemporal builtins

constexpr int BATCH  = 32;
constexpr int NPOSE  = 2048;
constexpr int KSAMP  = 32;             // samples per segment
constexpr int NSEG   = NPOSE - 1;      // 2047 segments
constexpr int NDELTA = NPOSE + 1;      // 2049 deltas
constexpr int SEGW   = 16;             // segments per WAVE (4096 waves total -> all resident)
constexpr int SUBR   = 8;              // segments per sub-round (64 lanes = 8 seg x 8 k-quads)
constexpr int NRND   = SEGW / SUBR;    // 2 sub-rounds, stage slice reused
constexpr int WAVES  = 4;              // waves per block
constexpr int SEGB   = SEGW * WAVES;   // 64 segments per block
constexpr int RSTRIDE = 6;             // float4s per delta record (24 words)
constexpr float EPS  = 1e-6f;
constexpr float EPS2 = 1e-12f;
constexpr float INV_TWO_PI = 0.15915494309189535f;

struct V3 { float x, y, z; };
struct Q4 { float x, y, z, w; };

__device__ __forceinline__ float frcp(float x)  { return __builtin_amdgcn_rcpf(x); }
__device__ __forceinline__ float fsqrt(float x) { return __builtin_amdgcn_sqrtf(x); }
__device__ __forceinline__ float fsin(float x)  { return __builtin_amdgcn_sinf(x * INV_TWO_PI); }
__device__ __forceinline__ float fcos(float x)  { return __builtin_amdgcn_cosf(x * INV_TWO_PI); }

__device__ __forceinline__ V3 v3add(V3 a, V3 b) { return {a.x + b.x, a.y + b.y, a.z + b.z}; }
__device__ __forceinline__ V3 v3sub(V3 a, V3 b) { return {a.x - b.x, a.y - b.y, a.z - b.z}; }
__device__ __forceinline__ V3 v3scl(V3 a, float s) { return {a.x * s, a.y * s, a.z * s}; }
__device__ __forceinline__ float v3dot(V3 a, V3 b) { return a.x * b.x + a.y * b.y + a.z * b.z; }
__device__ __forceinline__ V3 v3cross(V3 a, V3 b) {
    return {a.y * b.z - a.z * b.y, a.z * b.x - a.x * b.z, a.x * b.y - a.y * b.x};
}

__device__ __forceinline__ V3 qrot(Q4 q, V3 v) {
    V3 qv{q.x, q.y, q.z};
    V3 t = v3scl(v3cross(qv, v), 2.0f);
    return v3add(v3add(v, v3scl(t, q.w)), v3cross(qv, t));
}

__device__ __forceinline__ Q4 qmul(Q4 a, Q4 b) {
    return {a.w * b.x + a.x * b.w + a.y * b.z - a.z * b.y,
            a.w * b.y + a.y * b.w + a.z * b.x - a.x * b.z,
            a.w * b.z + a.z * b.w + a.x * b.y - a.y * b.x,
            a.w * b.w - a.x * b.x - a.y * b.y - a.z * b.z};
}

// fast acos, |err| <~ 7e-5 rad; for unit quats atan2(|qv|, w) == acos(w)
__device__ __forceinline__ float facos(float x) {
    float ax = fabsf(x);
    float p = -0.0012624911f;
    p = p * ax + 0.0066700901f;
    p = p * ax - 0.0170881256f;
    p = p * ax + 0.0308918810f;
    p = p * ax - 0.0501743046f;
    p = p * ax + 0.0889789874f;
    p = p * ax - 0.2145988016f;
    p = p * ax + 1.5707963050f;
    float r = fsqrt(fmaxf(1.0f - ax, 0.0f)) * p;
    return (x >= 0.0f) ? r : (3.14159265358979f - r);
}

__device__ __forceinline__ V3 so3_log(Q4 q) {
    V3 qv{q.x, q.y, q.z};
    float n2 = v3dot(qv, qv);
    bool small = n2 < EPS2;
    float n = fsqrt(small ? 1.0f : n2);
    float iw = frcp(q.w);
    float f_small = 2.0f * iw - (2.0f / 3.0f) * n2 * iw * iw * iw;
    float wc = fminf(fmaxf(q.w, -1.0f), 1.0f);
    float f_big = 2.0f * facos(wc) * frcp(n);
    return v3scl(qv, small ? f_small : f_big);
}

__device__ __forceinline__ V3 jl_inv(V3 phi, V3 v) {
    float t2 = v3dot(phi, phi);
    bool small = t2 < EPS2;
    float t2s = small ? 1.0f : t2;
    float theta = fsqrt(t2s);
    float s = fsin(theta), cth = fcos(theta);
    float s_safe = (fabsf(s) < EPS) ? EPS : s;
    float c_big = frcp(t2s) - (1.0f + cth) * frcp(2.0f * theta * s_safe);
    float c = small ? (1.0f / 12.0f + t2 * (1.0f / 720.0f)) : c_big;
    V3 c1 = v3cross(phi, v);
    return v3add(v3sub(v, v3scl(c1, 0.5f)), v3scl(v3cross(phi, c1), c));
}

// ---- packed-fp32 SE(3) over 2 k-samples (lanes of each f2) ----
struct V3p { f2 x, y, z; };
struct Q4p { f2 x, y, z, w; };
struct SE3p { V3p t; Q4p q; };

__device__ __forceinline__ f2 splat(float a) { return f2{a, a}; }

__device__ __forceinline__ SE3p se3_mul_p(const SE3p& A, const SE3p& B) {
    f2 cx = A.q.y * B.t.z - A.q.z * B.t.y;
    f2 cy = A.q.z * B.t.x - A.q.x * B.t.z;
    f2 cz = A.q.x * B.t.y - A.q.y * B.t.x;
    cx = cx + cx; cy = cy + cy; cz = cz + cz;
    SE3p r;
    r.t.x = A.t.x + B.t.x + A.q.w * cx + (A.q.y * cz - A.q.z * cy);
    r.t.y = A.t.y + B.t.y + A.q.w * cy + (A.q.z * cx - A.q.x * cz);
    r.t.z = A.t.z + B.t.z + A.q.w * cz + (A.q.x * cy - A.q.y * cx);
    r.q.x = A.q.w * B.q.x + A.q.x * B.q.w + A.q.y * B.q.z - A.q.z * B.q.y;
    r.q.y = A.q.w * B.q.y + A.q.y * B.q.w + A.q.z * B.q.x - A.q.x * B.q.z;
    r.q.z = A.q.w * B.q.z + A.q.z * B.q.w + A.q.x * B.q.y - A.q.y * B.q.x;
    r.q.w = A.q.w * B.q.w - A.q.x * B.q.x - A.q.y * B.q.y - A.q.z * B.q.z;
    return r;
}

__device__ __forceinline__ SE3p build_E(const float4& A, const float4& U,
                                        const float4& C1, const float4& C2,
                                        float wa, float wb) {
    const float inv_n = U.w;                   // per-delta 1/nphi
    float tha = wa * A.w, thb = wb * A.w;      // th = w * nphi
    float sa = fsin(0.5f * tha), ca = fcos(0.5f * tha);
    float sb = fsin(0.5f * thb), cb = fcos(0.5f * thb);
    float cAa = 2.0f * sa * sa * inv_n;        // (1 - cos th)/n
    float cAb = 2.0f * sb * sb * inv_n;
    float cBa = (tha - 2.0f * sa * ca) * inv_n; // (th - sin th)/n
    float cBb = (thb - 2.0f * sb * cb) * inv_n;
    f2 s2{sa, sb}, c2{ca, cb};
    f2 cA{cAa, cAb}, cB{cBa, cBb}, wh{wa, wb};
    SE3p E;
    E.q.x = s2 * splat(U.x); E.q.y = s2 * splat(U.y); E.q.z = s2 * splat(U.z);
    E.q.w = c2;
    E.t.x = wh * splat(A.x) + cA * splat(C1.x) + cB * splat(C2.x);
    E.t.y = wh * splat(A.y) + cA * splat(C1.y) + cB * splat(C2.y);
    E.t.z = wh * splat(A.z) + cA * splat(C1.z) + cB * splat(C2.z);
    return E;
}

// ------------- all-resident wave-autonomous kernel (ZERO barriers) -------------
// 4096 waves total == residency capacity (4 blk/CU x 4 waves x 256 CU): the whole
// grid runs as ONE dispatch round -> no tail (R2/R3 ran as 2 rounds; the 2nd was
// ~65% full, costing ~2x per-block latency).
// Each 64-lane wave owns 16 segments:
//   A: lanes 0..17 compute the 18 delta records its segments need (private LDS)
//   2x sub-rounds of 8 segments, REUSING one 7KB stage slice:
//     B: lane = (segl 0..7, k-quad 0..7) packed-fp32 compose -> stage slice
//     C: wave copies slice to global, stride-1 nontemporal f4
// Same-wave DS in-order execution makes B->C->B(overwrite) safe with no barriers
// (validated by R3 passing). __launch_bounds__(256,4) pins VGPR<=128 so wave
// slots, not registers, set occupancy.
__global__ __launch_bounds__(256, 4) void lie_spline_fused(
    const float* __restrict__ poses,   // [B, N, 7]
    const float* __restrict__ timev,   // [K]
    float* __restrict__ out)           // [B, S*K, 7]
{
    __shared__ float4 sdel[WAVES][(SEGW + 2) * RSTRIDE];           // 4 x 1728 B
    __shared__ __align__(16) float stage[WAVES][SUBR * KSAMP * 7]; // 4 x 7168 B  (34.75 KB total)

    const int b    = blockIdx.y;
    const int tid  = threadIdx.x;
    const int wid  = tid >> 6;                   // wave 0..3
    const int lane = tid & 63;
    const int sW   = blockIdx.x * SEGB + wid * SEGW;   // wave's first segment
    const int segl = lane >> 3;                  // 0..7 within sub-round
    const int m    = lane & 7;                   // k-quad index

    const float4 uvec = reinterpret_cast<const float4*>(timev)[m];

    // ---- Phase A (lanes 0..17; exec-masked) ----
    if (lane < SEGW + 2) {
        int i = min(sW + lane, NDELTA - 1);
        int ia = max(i - 1, 0);
        int ib = min(i, NPOSE - 1);
        const float* Pa = poses + ((size_t)b * NPOSE + ia) * 7;
        const float* Pb = poses + ((size_t)b * NPOSE + ib) * 7;
        V3 ta{Pa[0], Pa[1], Pa[2]}; Q4 qa{Pa[3], Pa[4], Pa[5], Pa[6]};
        V3 tb{Pb[0], Pb[1], Pb[2]}; Q4 qb{Pb[3], Pb[4], Pb[5], Pb[6]};

        Q4 qi{-qa.x, -qa.y, -qa.z, qa.w};
        V3 trel = qrot(qi, v3sub(tb, ta));
        Q4 qrel = qmul(qi, qb);
        V3 phi = so3_log(qrel);
        V3 tau = jl_inv(phi, trel);

        float nphi = fsqrt(v3dot(phi, phi));
        float inv_n = frcp(fmaxf(nphi, 1e-20f)); // identity: phi=0 -> u=c1=c2=0 exactly
        V3 u  = v3scl(phi, inv_n);
        V3 c1 = v3cross(u, tau);
        V3 c2 = v3cross(u, c1);

        float4* r = sdel[wid] + lane * RSTRIDE;
        r[0] = make_float4(tau.x, tau.y, tau.z, nphi);
        r[1] = make_float4(u.x,  u.y,  u.z,  inv_n);
        r[2] = make_float4(c1.x, c1.y, c1.z, 0.0f);
        r[3] = make_float4(c2.x, c2.y, c2.z, 0.0f);
        r[4] = make_float4(ta.x, ta.y, ta.z, qa.x);   // Pa == p0 of segment (sW+lane)
        r[5] = make_float4(qa.y, qa.z, qa.w, 0.0f);
    }
    // no barrier: same-wave LDS write->read (in-order DS pipeline + lgkmcnt)

    #pragma unroll 1
    for (int rr = 0; rr < NRND; ++rr) {
        const int sloc = rr * SUBR + segl;               // local segment 0..15
        // ---- Phase B (unguarded; clamped records make tail segments defined) ----
        {
            const float4* R = sdel[wid] + sloc * RSTRIDE;
            const float4 A0 = R[0],             U0 = R[1],               C10 = R[2],               C20 = R[3];
            const float4 P03 = R[4],            P46 = R[5];
            const float4 A1 = R[RSTRIDE],       U1 = R[RSTRIDE + 1],     C11 = R[RSTRIDE + 2],     C21 = R[RSTRIDE + 3];
            const float4 A2 = R[2 * RSTRIDE],   U2 = R[2 * RSTRIDE + 1], C12 = R[2 * RSTRIDE + 2], C22 = R[2 * RSTRIDE + 3];

            SE3p Tph;
            Tph.t.x = splat(P03.x); Tph.t.y = splat(P03.y); Tph.t.z = splat(P03.z);
            Tph.q.x = splat(P03.w); Tph.q.y = splat(P46.x); Tph.q.z = splat(P46.y);
            Tph.q.w = splat(P46.z);

            const float c6 = 1.0f / 6.0f;
            #define CHAIN(ua_, ub_, Tdst_)                                           \
            {                                                                        \
                float ua = (ua_), ub = (ub_);                                        \
                float ua2 = ua * ua, ua3 = ua2 * ua;                                 \
                float ub2 = ub * ub, ub3 = ub2 * ub;                                 \
                float w0a = (5.0f + 3.0f * ua - 3.0f * ua2 + ua3) * c6;              \
                float w0b = (5.0f + 3.0f * ub - 3.0f * ub2 + ub3) * c6;              \
                float w1a = (1.0f + 3.0f * ua + 3.0f * ua2 - 2.0f * ua3) * c6;       \
                float w1b = (1.0f + 3.0f * ub + 3.0f * ub2 - 2.0f * ub3) * c6;       \
                float w2a = ua3 * c6, w2b = ub3 * c6;                                \
                SE3p T = se3_mul_p(Tph, build_E(A0, U0, C10, C20, w0a, w0b));        \
                T = se3_mul_p(T, build_E(A1, U1, C11, C21, w1a, w1b));               \
                T = se3_mul_p(T, build_E(A2, U2, C12, C22, w2a, w2b));               \
                Tdst_ = T;                                                           \
            }

            float* sb_ = stage[wid] + segl * (KSAMP * 7) + m * 28;
            float4* sv = reinterpret_cast<float4*>(sb_);
            float2* s2v = reinterpret_cast<float2*>(sb_);

            // pair 0: k = 4m, 4m+1 (lanes [0],[1]); 3x f4 + f2 tail
            {
                SE3p TA;
                CHAIN(uvec.x, uvec.y, TA)
                sv[0]  = make_float4(TA.t.x[0], TA.t.y[0], TA.t.z[0], TA.q.x[0]);
                sv[1]  = make_float4(TA.q.y[0], TA.q.z[0], TA.q.w[0], TA.t.x[1]);
                sv[2]  = make_float4(TA.t.y[1], TA.t.z[1], TA.q.x[1], TA.q.y[1]);
                s2v[6] = make_float2(TA.q.z[1], TA.q.w[1]);
            }
            // pair 1: k = 4m+2, 4m+3; f2 head + 3x f4
            {
                SE3p TB;
                CHAIN(uvec.z, uvec.w, TB)
                s2v[7] = make_float2(TB.t.x[0], TB.t.y[0]);
                sv[4]  = make_float4(TB.t.z[0], TB.q.x[0], TB.q.y[0], TB.q.z[0]);
                sv[5]  = make_float4(TB.q.w[0], TB.t.x[1], TB.t.y[1], TB.t.z[1]);
                sv[6]  = make_float4(TB.q.x[1], TB.q.y[1], TB.q.z[1], TB.q.w[1]);
            }
            #undef CHAIN
        }
        // no barrier: Phase C reads this wave's own slice (in-order DS)

        // ---- Phase C: copy wave's 7KB slice, stride-1 nontemporal f4 ----
        {
            const int sBase = sW + rr * SUBR;
            const int nseg_w = min(NSEG - sBase, SUBR);      // <=0 only for clamped tail
            if (nseg_w > 0) {
                const int nvec = nseg_w * (KSAMP * 7 / 4);   // 56 float4 per segment
                const f4* svv = reinterpret_cast<const f4*>(stage[wid]);
                f4* ov = reinterpret_cast<f4*>(out + ((size_t)b * NSEG + sBase) * (size_t)(KSAMP * 7));
                for (int j = lane; j < nvec; j += 64)
                    __builtin_nontemporal_store(svv[j], ov + j);  // write-once output: skip L2 dirty residency
            }
        }
        // sub-round 1 overwrites the stage slice only after this wave's reads
        // executed (in-order DS pipeline) -- no WAR hazard, no barrier.
    }
}

} // namespace

extern "C" void kernel_launch(void* const* d_in, const int* in_sizes, int n_in,
                              void* d_out, int out_size, void* d_ws, size_t ws_size,
                              hipStream_t stream) {
    const float* poses = (const float*)d_in[0];   // [32, 2048, 7] fp32
    const float* timev = (const float*)d_in[1];   // [32] fp32
    float* out = (float*)d_out;                   // [32, 2047*32, 7] fp32
    (void)in_sizes; (void)n_in; (void)out_size; (void)d_ws; (void)ws_size;

    dim3 grid((NSEG + SEGB - 1) / SEGB, BATCH);   // (32, 32) = 1024 blocks, all resident
    lie_spline_fused<<<grid, 256, 0, stream>>>(poses, timev, out);
}